// Round 1
// baseline (4545.854 us; speedup 1.0000x reference)
//
#include <hip/hip_runtime.h>
#include <hip/hip_bf16.h>
#include <math.h>

#define NTOKEN 60697
#define D_MODEL 512
#define NLAYERS 4
#define D_STATE 16
#define D_CONV 4
#define D_INNER 1024
#define DT_RANK 32
#define B_SZ 4
#define SEQ 2048
#define EPS 1e-5f
#define NROWS (B_SZ * SEQ)   // 8192

// ---------------- utilities ----------------

__device__ __forceinline__ float fast_sigmoid(float x) {
    return 1.0f / (1.0f + __expf(-x));
}
__device__ __forceinline__ float silu(float x) {
    return x * fast_sigmoid(x);
}
__device__ __forceinline__ float softplus_f(float x) {
    return (x > 20.0f) ? x : log1pf(__expf(x));
}

// block of 256 threads (4 waves). sbuf must be float[4] shared.
__device__ __forceinline__ float blk_reduce_sum(float x, float* sbuf) {
#pragma unroll
    for (int m = 32; m >= 1; m >>= 1) x += __shfl_xor(x, m);
    int wid = threadIdx.x >> 6;
    if ((threadIdx.x & 63) == 0) sbuf[wid] = x;
    __syncthreads();
    float t = sbuf[0] + sbuf[1] + sbuf[2] + sbuf[3];
    __syncthreads();
    return t;
}

// ---------------- embedding + layernorm ----------------

__global__ __launch_bounds__(256) void embed_ln_kernel(
    const int* __restrict__ src, const float* __restrict__ emb,
    const float* __restrict__ w, const float* __restrict__ b,
    float* __restrict__ R)
{
    __shared__ float sbuf[4];
    int row = blockIdx.x;
    int tok = src[row];
    const float* e = emb + (size_t)tok * D_MODEL;
    int c0 = threadIdx.x, c1 = threadIdx.x + 256;
    float v0 = e[c0], v1 = e[c1];
    float mu = blk_reduce_sum(v0 + v1, sbuf) * (1.0f / D_MODEL);
    float d0 = v0 - mu, d1 = v1 - mu;
    float var = blk_reduce_sum(d0 * d0 + d1 * d1, sbuf) * (1.0f / D_MODEL);
    float rs = rsqrtf(var + EPS);
    size_t base = (size_t)row * D_MODEL;
    R[base + c0] = d0 * rs * w[c0] + b[c0];
    R[base + c1] = d1 * rs * w[c1] + b[c1];
}

// optional residual add (R += Hadd), then LN(R) -> out
__global__ __launch_bounds__(256) void add_ln_kernel(
    float* __restrict__ R, const float* __restrict__ Hadd,
    const float* __restrict__ w, const float* __restrict__ b,
    float* __restrict__ out)
{
    __shared__ float sbuf[4];
    size_t base = (size_t)blockIdx.x * D_MODEL;
    int c0 = threadIdx.x, c1 = c0 + 256;
    float v0 = R[base + c0], v1 = R[base + c1];
    if (Hadd) {
        v0 += Hadd[base + c0];
        v1 += Hadd[base + c1];
        R[base + c0] = v0;
        R[base + c1] = v1;
    }
    float mu = blk_reduce_sum(v0 + v1, sbuf) * (1.0f / D_MODEL);
    float d0 = v0 - mu, d1 = v1 - mu;
    float var = blk_reduce_sum(d0 * d0 + d1 * d1, sbuf) * (1.0f / D_MODEL);
    float rs = rsqrtf(var + EPS);
    out[base + c0] = d0 * rs * w[c0] + b[c0];
    out[base + c1] = d1 * rs * w[c1] + b[c1];
}

// ---------------- generic NT GEMM ----------------
// C[m][n] = sum_k A[m][k] * B[n][k]   (+ epilogue)
// EPI: 0 = store, 1 = softplus(x + bias[n])
// Tile 64x64, BK=16, 256 threads, 4x4 per thread. M,N mult of 64, K mult of 16.
template <int EPI>
__global__ __launch_bounds__(256) void gemm_nt(
    const float* __restrict__ A, int lda,
    const float* __restrict__ B, int ldb,
    float* __restrict__ C, int ldc,
    int K, const float* __restrict__ bias)
{
    __shared__ float As[64][17];
    __shared__ float Bs[64][17];
    int tid = threadIdx.x;
    int tx = tid & 15, ty = tid >> 4;
    int m0 = blockIdx.y * 64, n0 = blockIdx.x * 64;
    float acc[4][4] = {};
    for (int k0 = 0; k0 < K; k0 += 16) {
#pragma unroll
        for (int i = 0; i < 4; i++) {
            int idx = tid + i * 256;
            int row = idx >> 4, kk = idx & 15;
            As[row][kk] = A[(size_t)(m0 + row) * lda + k0 + kk];
            Bs[row][kk] = B[(size_t)(n0 + row) * ldb + k0 + kk];
        }
        __syncthreads();
#pragma unroll
        for (int kk = 0; kk < 16; kk++) {
            float a[4], b[4];
#pragma unroll
            for (int i = 0; i < 4; i++) a[i] = As[ty * 4 + i][kk];
#pragma unroll
            for (int j = 0; j < 4; j++) b[j] = Bs[tx * 4 + j][kk];
#pragma unroll
            for (int i = 0; i < 4; i++)
#pragma unroll
                for (int j = 0; j < 4; j++) acc[i][j] += a[i] * b[j];
        }
        __syncthreads();
    }
#pragma unroll
    for (int i = 0; i < 4; i++) {
        int m = m0 + ty * 4 + i;
#pragma unroll
        for (int j = 0; j < 4; j++) {
            int n = n0 + tx * 4 + j;
            float v = acc[i][j];
            if (EPI == 1) v = softplus_f(v + bias[n]);
            C[(size_t)m * ldc + n] = v;
        }
    }
}

// ---------------- causal depthwise conv + silu ----------------
// XZ rows are (b*SEQ+t), width 2*D_INNER; x = cols [0,1024)
__global__ __launch_bounds__(256) void conv_silu_kernel(
    const float* __restrict__ XZ, const float* __restrict__ cw,
    const float* __restrict__ cb, float* __restrict__ XC)
{
    size_t gid = (size_t)blockIdx.x * 256 + threadIdx.x;  // over NROWS*D_INNER
    int d = (int)(gid & (D_INNER - 1));
    size_t bt = gid >> 10;
    int t = (int)(bt & (SEQ - 1));
    float acc = cb[d];
#pragma unroll
    for (int k = 0; k < D_CONV; k++) {
        int tt = t + k - (D_CONV - 1);
        if (tt >= 0)
            acc += cw[d * D_CONV + k] * XZ[(bt + (size_t)(k - (D_CONV - 1))) * (2 * D_INNER) + d];
    }
    XC[gid] = silu(acc);
}

// ---------------- selective scan ----------------
// block: 16 channels (d) x 16 states (s) = 256 threads; grid = B_SZ * (D_INNER/16)
// y written in-place into DT (each dt consumed from LDS stage before write).
__global__ __launch_bounds__(256) void scan_kernel(
    float* __restrict__ DT, const float* __restrict__ XC,
    const float* __restrict__ XD, const float* __restrict__ A_log)
{
    __shared__ float sdt[64][16];
    __shared__ float sx[64][16];
    __shared__ float sB[64][16];
    __shared__ float sC[64][16];
    int tid = threadIdx.x;
    int s = tid & 15, dl = tid >> 4;
    int blk = blockIdx.x;
    int b = blk >> 6;          // / (D_INNER/16)
    int d0 = (blk & 63) * 16;
    int d = d0 + dl;
    float Av = -__expf(A_log[d * D_STATE + s]);
    float h = 0.0f;
    size_t bbase = (size_t)b * SEQ;
    for (int t0 = 0; t0 < SEQ; t0 += 64) {
#pragma unroll
        for (int i = 0; i < 4; i++) {
            int idx = tid + i * 256;
            int tt = idx >> 4, c = idx & 15;
            size_t row = bbase + t0 + tt;
            sdt[tt][c] = DT[row * D_INNER + d0 + c];
            sx[tt][c]  = XC[row * D_INNER + d0 + c];
            sB[tt][c]  = XD[row * 64 + DT_RANK + c];
            sC[tt][c]  = XD[row * 64 + DT_RANK + D_STATE + c];
        }
        __syncthreads();
        for (int tt = 0; tt < 64; tt++) {
            float dtv = sdt[tt][dl];
            float xv  = sx[tt][dl];
            h = __expf(dtv * Av) * h + (dtv * xv) * sB[tt][s];
            float p = h * sC[tt][s];
            p += __shfl_xor(p, 1);
            p += __shfl_xor(p, 2);
            p += __shfl_xor(p, 4);
            p += __shfl_xor(p, 8);
            if (s == 0) DT[(bbase + t0 + tt) * D_INNER + d] = p;
        }
        __syncthreads();
    }
}

// ---------------- combine: y = (y + x*Dskip) * silu(z) ----------------
__global__ __launch_bounds__(256) void combine_kernel(
    const float* __restrict__ Y, float* __restrict__ XC,
    const float* __restrict__ XZ, const float* __restrict__ Dskip)
{
    size_t gid = (size_t)blockIdx.x * 256 + threadIdx.x;  // over NROWS*D_INNER
    int d = (int)(gid & (D_INNER - 1));
    size_t bt = gid >> 10;
    float z = XZ[bt * (2 * D_INNER) + D_INNER + d];
    float y = Y[gid] + XC[gid] * Dskip[d];
    XC[gid] = y * silu(z);
}

// ---------------- launch ----------------

extern "C" void kernel_launch(void* const* d_in, const int* in_sizes, int n_in,
                              void* d_out, int out_size, void* d_ws, size_t ws_size,
                              hipStream_t stream) {
    const int*   src       = (const int*)d_in[0];
    const float* emb_w     = (const float*)d_in[2];
    const float* enc_ln_w  = (const float*)d_in[3];
    const float* enc_ln_b  = (const float*)d_in[4];
    const float* ln_w      = (const float*)d_in[5];
    const float* ln_b      = (const float*)d_in[6];
    const float* in_proj_w = (const float*)d_in[7];
    const float* conv_w    = (const float*)d_in[8];
    const float* conv_b    = (const float*)d_in[9];
    const float* x_proj_w  = (const float*)d_in[10];
    const float* dt_proj_w = (const float*)d_in[11];
    const float* dt_proj_b = (const float*)d_in[12];
    const float* A_log     = (const float*)d_in[13];
    const float* D_skip    = (const float*)d_in[14];
    const float* out_proj_w= (const float*)d_in[15];
    const float* normf_w   = (const float*)d_in[16];
    const float* normf_b   = (const float*)d_in[17];
    float* out = (float*)d_out;

    float* R  = (float*)d_ws;                 // 8192*512
    float* H  = R  + (size_t)NROWS * D_MODEL; // 8192*512
    float* XZ = H  + (size_t)NROWS * D_MODEL; // 8192*2048
    float* XC = XZ + (size_t)NROWS * 2 * D_INNER; // 8192*1024
    float* XD = XC + (size_t)NROWS * D_INNER; // 8192*64
    float* DT = XD + (size_t)NROWS * 64;      // 8192*1024

    embed_ln_kernel<<<NROWS, 256, 0, stream>>>(src, emb_w, enc_ln_w, enc_ln_b, R);

    for (int L = 0; L < NLAYERS; L++) {
        // residual add (except layer 0) + LN -> H
        add_ln_kernel<<<NROWS, 256, 0, stream>>>(
            R, (L == 0) ? nullptr : H, ln_w + L * D_MODEL, ln_b + L * D_MODEL, H);

        // in_proj: H(8192x512) @ W^T(512->2048) -> XZ
        gemm_nt<0><<<dim3(2 * D_INNER / 64, NROWS / 64), 256, 0, stream>>>(
            H, D_MODEL, in_proj_w + (size_t)L * 2 * D_INNER * D_MODEL, D_MODEL,
            XZ, 2 * D_INNER, D_MODEL, nullptr);

        // conv + silu -> XC
        conv_silu_kernel<<<(NROWS * D_INNER) / 256, 256, 0, stream>>>(
            XZ, conv_w + (size_t)L * D_INNER * D_CONV, conv_b + (size_t)L * D_INNER, XC);

        // x_proj: XC(8192x1024) @ W^T(1024->64) -> XD
        gemm_nt<0><<<dim3(64 / 64, NROWS / 64), 256, 0, stream>>>(
            XC, D_INNER, x_proj_w + (size_t)L * 64 * D_INNER, D_INNER,
            XD, 64, D_INNER, nullptr);

        // dt_proj + softplus: XD[:, :32](8192x32) @ W^T(32->1024) + b -> DT
        gemm_nt<1><<<dim3(D_INNER / 64, NROWS / 64), 256, 0, stream>>>(
            XD, 64, dt_proj_w + (size_t)L * D_INNER * DT_RANK, DT_RANK,
            DT, D_INNER, DT_RANK, dt_proj_b + (size_t)L * D_INNER);

        // selective scan (y in-place into DT)
        scan_kernel<<<B_SZ * (D_INNER / 16), 256, 0, stream>>>(
            DT, XC, XD, A_log + (size_t)L * D_INNER * D_STATE);

        // combine -> XC
        combine_kernel<<<(NROWS * D_INNER) / 256, 256, 0, stream>>>(
            DT, XC, XZ, D_skip + (size_t)L * D_INNER);

        // out_proj: XC(8192x1024) @ W^T(1024->512) -> H
        gemm_nt<0><<<dim3(D_MODEL / 64, NROWS / 64), 256, 0, stream>>>(
            XC, D_INNER, out_proj_w + (size_t)L * D_MODEL * D_INNER, D_INNER,
            H, D_MODEL, D_INNER, nullptr);
    }

    // final residual add + LN -> out
    add_ln_kernel<<<NROWS, 256, 0, stream>>>(R, H, normf_w, normf_b, out);
}

// Round 2
// 2772.871 us; speedup vs baseline: 1.6394x; 1.6394x over previous
//
#include <hip/hip_runtime.h>
#include <hip/hip_bf16.h>
#include <math.h>

#define NTOKEN 60697
#define D_MODEL 512
#define NLAYERS 4
#define D_STATE 16
#define D_CONV 4
#define D_INNER 1024
#define DT_RANK 32
#define B_SZ 4
#define SEQ 2048
#define EPS 1e-5f
#define NROWS (B_SZ * SEQ)   // 8192

typedef __bf16 bf16_t;
typedef __attribute__((ext_vector_type(8))) __bf16 bfx8;
typedef __attribute__((ext_vector_type(4))) __bf16 bfx4;
typedef __attribute__((ext_vector_type(4))) float f32x4;

// ---------------- utilities ----------------

__device__ __forceinline__ float fast_sigmoid(float x) {
    return 1.0f / (1.0f + __expf(-x));
}
__device__ __forceinline__ float silu(float x) {
    return x * fast_sigmoid(x);
}
__device__ __forceinline__ float softplus_f(float x) {
    return (x > 20.0f) ? x : log1pf(__expf(x));
}

__device__ __forceinline__ void gload_lds16(const void* g, void* l) {
    __builtin_amdgcn_global_load_lds(
        (const __attribute__((address_space(1))) unsigned int*)g,
        (__attribute__((address_space(3))) unsigned int*)l, 16, 0, 0);
}

// block of 256 threads (4 waves). sbuf must be float[4] shared.
__device__ __forceinline__ float blk_reduce_sum(float x, float* sbuf) {
#pragma unroll
    for (int m = 32; m >= 1; m >>= 1) x += __shfl_xor(x, m);
    int wid = threadIdx.x >> 6;
    if ((threadIdx.x & 63) == 0) sbuf[wid] = x;
    __syncthreads();
    float t = sbuf[0] + sbuf[1] + sbuf[2] + sbuf[3];
    __syncthreads();
    return t;
}

// ---------------- fp32 -> bf16 cast (RNE), vector x4 ----------------
__global__ __launch_bounds__(256) void cast_bf16_kernel(
    const float* __restrict__ in, bf16_t* __restrict__ out, size_t n)
{
    size_t stride = (size_t)gridDim.x * 256 * 4;
    for (size_t i = ((size_t)blockIdx.x * 256 + threadIdx.x) * 4; i < n; i += stride) {
        float4 v = *reinterpret_cast<const float4*>(in + i);
        bfx4 o;
        o[0] = (bf16_t)v.x; o[1] = (bf16_t)v.y;
        o[2] = (bf16_t)v.z; o[3] = (bf16_t)v.w;
        *reinterpret_cast<bfx4*>(out + i) = o;
    }
}

// ---------------- embedding + layernorm ----------------

__global__ __launch_bounds__(256) void embed_ln_kernel(
    const int* __restrict__ src, const float* __restrict__ emb,
    const float* __restrict__ w, const float* __restrict__ b,
    float* __restrict__ R)
{
    __shared__ float sbuf[4];
    int row = blockIdx.x;
    int tok = src[row];
    const float* e = emb + (size_t)tok * D_MODEL;
    int c0 = threadIdx.x, c1 = threadIdx.x + 256;
    float v0 = e[c0], v1 = e[c1];
    float mu = blk_reduce_sum(v0 + v1, sbuf) * (1.0f / D_MODEL);
    float d0 = v0 - mu, d1 = v1 - mu;
    float var = blk_reduce_sum(d0 * d0 + d1 * d1, sbuf) * (1.0f / D_MODEL);
    float rs = rsqrtf(var + EPS);
    size_t base = (size_t)row * D_MODEL;
    R[base + c0] = d0 * rs * w[c0] + b[c0];
    R[base + c1] = d1 * rs * w[c1] + b[c1];
}

// optional residual add (R += Hadd), then LN(R) -> out (fp32) and outb (bf16, optional)
__global__ __launch_bounds__(256) void add_ln_kernel(
    float* __restrict__ R, const float* __restrict__ Hadd,
    const float* __restrict__ w, const float* __restrict__ b,
    float* __restrict__ out, bf16_t* __restrict__ outb)
{
    __shared__ float sbuf[4];
    size_t base = (size_t)blockIdx.x * D_MODEL;
    int c0 = threadIdx.x, c1 = c0 + 256;
    float v0 = R[base + c0], v1 = R[base + c1];
    if (Hadd) {
        v0 += Hadd[base + c0];
        v1 += Hadd[base + c1];
        R[base + c0] = v0;
        R[base + c1] = v1;
    }
    float mu = blk_reduce_sum(v0 + v1, sbuf) * (1.0f / D_MODEL);
    float d0 = v0 - mu, d1 = v1 - mu;
    float var = blk_reduce_sum(d0 * d0 + d1 * d1, sbuf) * (1.0f / D_MODEL);
    float rs = rsqrtf(var + EPS);
    float o0 = d0 * rs * w[c0] + b[c0];
    float o1 = d1 * rs * w[c1] + b[c1];
    if (out) {
        out[base + c0] = o0;
        out[base + c1] = o1;
    }
    if (outb) {
        outb[base + c0] = (bf16_t)o0;
        outb[base + c1] = (bf16_t)o1;
    }
}

// ---------------- bf16 MFMA GEMM (NT): C[m][n] = sum_k A[m][k]*B[n][k] ----------------
// m97 structure: 128x128 tile, BK=32, 256 threads (4 waves 2x2, 64x64 each),
// global_load_lds width 16, mfma_f32_16x16x32_bf16, fp32 output.
// M % 128 == 0, N % 128 == 0, K % 32 == 0. ldc = N.
__global__ __launch_bounds__(256) void gemm_bf16_nt(
    const bf16_t* __restrict__ A, const bf16_t* __restrict__ B,
    float* __restrict__ C, int ldc, int K)
{
    __shared__ bf16_t As[128 * 32];
    __shared__ bf16_t Bs[128 * 32];
    int tid = threadIdx.x;
    int lane = tid & 63, wid = tid >> 6;
    int m0 = blockIdx.y * 128, n0 = blockIdx.x * 128;
    int wm = (wid >> 1) * 64, wn = (wid & 1) * 64;
    int c_lo = lane & 15;   // fragment row (A) / col (B,D)
    int khalf = lane >> 4;  // 0..3: k-subgroup (8 elems) and D row-group

    f32x4 acc[4][4];
#pragma unroll
    for (int i = 0; i < 4; i++)
#pragma unroll
        for (int j = 0; j < 4; j++)
            acc[i][j] = (f32x4){0.f, 0.f, 0.f, 0.f};

    for (int k0 = 0; k0 < K; k0 += 32) {
        // stage A,B tiles: [128][32] bf16 linear = 8192 B each; 512 chunks of 16 B
#pragma unroll
        for (int i = 0; i < 2; i++) {
            int c = i * 256 + tid;            // chunk id: lds byte = c*16
            int row = c >> 2;                 // 4 chunks per 64B row
            int cb = (c & 3) * 16;            // byte offset within row
            int ldsoff = (i * 256 + wid * 64) * 16;  // wave-uniform base
            gload_lds16((const char*)A + ((size_t)(m0 + row) * K + k0) * 2 + cb,
                        (char*)As + ldsoff);
            gload_lds16((const char*)B + ((size_t)(n0 + row) * K + k0) * 2 + cb,
                        (char*)Bs + ldsoff);
        }
        __syncthreads();   // compiler emits vmcnt(0) drain before barrier

        bfx8 af[4], bfr[4];
#pragma unroll
        for (int i = 0; i < 4; i++) {
            af[i]  = *reinterpret_cast<const bfx8*>(As + (wm + i * 16 + c_lo) * 32 + khalf * 8);
            bfr[i] = *reinterpret_cast<const bfx8*>(Bs + (wn + i * 16 + c_lo) * 32 + khalf * 8);
        }
#pragma unroll
        for (int i = 0; i < 4; i++)
#pragma unroll
            for (int j = 0; j < 4; j++)
                acc[i][j] = __builtin_amdgcn_mfma_f32_16x16x32_bf16(af[i], bfr[j], acc[i][j], 0, 0, 0);
        __syncthreads();
    }

    // C write: row=(lane>>4)*4+reg, col=lane&15 within each 16x16 fragment
#pragma unroll
    for (int i = 0; i < 4; i++) {
#pragma unroll
        for (int j = 0; j < 4; j++) {
            int row0 = m0 + wm + i * 16 + khalf * 4;
            int col = n0 + wn + j * 16 + c_lo;
#pragma unroll
            for (int r = 0; r < 4; r++)
                C[(size_t)(row0 + r) * ldc + col] = acc[i][j][r];
        }
    }
}

// ---------------- generic fp32 NT GEMM (small matmuls) ----------------
template <int EPI>
__global__ __launch_bounds__(256) void gemm_nt(
    const float* __restrict__ A, int lda,
    const float* __restrict__ B, int ldb,
    float* __restrict__ C, int ldc,
    int K, const float* __restrict__ bias)
{
    __shared__ float As[64][17];
    __shared__ float Bs[64][17];
    int tid = threadIdx.x;
    int tx = tid & 15, ty = tid >> 4;
    int m0 = blockIdx.y * 64, n0 = blockIdx.x * 64;
    float acc[4][4] = {};
    for (int k0 = 0; k0 < K; k0 += 16) {
#pragma unroll
        for (int i = 0; i < 4; i++) {
            int idx = tid + i * 256;
            int row = idx >> 4, kk = idx & 15;
            As[row][kk] = A[(size_t)(m0 + row) * lda + k0 + kk];
            Bs[row][kk] = B[(size_t)(n0 + row) * ldb + k0 + kk];
        }
        __syncthreads();
#pragma unroll
        for (int kk = 0; kk < 16; kk++) {
            float a[4], b[4];
#pragma unroll
            for (int i = 0; i < 4; i++) a[i] = As[ty * 4 + i][kk];
#pragma unroll
            for (int j = 0; j < 4; j++) b[j] = Bs[tx * 4 + j][kk];
#pragma unroll
            for (int i = 0; i < 4; i++)
#pragma unroll
                for (int j = 0; j < 4; j++) acc[i][j] += a[i] * b[j];
        }
        __syncthreads();
    }
#pragma unroll
    for (int i = 0; i < 4; i++) {
        int m = m0 + ty * 4 + i;
#pragma unroll
        for (int j = 0; j < 4; j++) {
            int n = n0 + tx * 4 + j;
            float v = acc[i][j];
            if (EPI == 1) v = softplus_f(v + bias[n]);
            C[(size_t)m * ldc + n] = v;
        }
    }
}

// ---------------- causal depthwise conv + silu ----------------
__global__ __launch_bounds__(256) void conv_silu_kernel(
    const float* __restrict__ XZ, const float* __restrict__ cw,
    const float* __restrict__ cb, float* __restrict__ XC, bf16_t* __restrict__ XCb)
{
    size_t gid = (size_t)blockIdx.x * 256 + threadIdx.x;  // over NROWS*D_INNER
    int d = (int)(gid & (D_INNER - 1));
    size_t bt = gid >> 10;
    int t = (int)(bt & (SEQ - 1));
    float acc = cb[d];
#pragma unroll
    for (int k = 0; k < D_CONV; k++) {
        int tt = t + k - (D_CONV - 1);
        if (tt >= 0)
            acc += cw[d * D_CONV + k] * XZ[(bt + (size_t)(k - (D_CONV - 1))) * (2 * D_INNER) + d];
    }
    float v = silu(acc);
    XC[gid] = v;
    XCb[gid] = (bf16_t)v;  // unused this round's bf16 path for x_proj, kept for out_proj input cast fusion later
}

// ---------------- selective scan ----------------
__global__ __launch_bounds__(256) void scan_kernel(
    float* __restrict__ DT, const float* __restrict__ XC,
    const float* __restrict__ XD, const float* __restrict__ A_log)
{
    __shared__ float sdt[64][16];
    __shared__ float sx[64][16];
    __shared__ float sB[64][16];
    __shared__ float sC[64][16];
    int tid = threadIdx.x;
    int s = tid & 15, dl = tid >> 4;
    int blk = blockIdx.x;
    int b = blk >> 6;
    int d0 = (blk & 63) * 16;
    int d = d0 + dl;
    float Av = -__expf(A_log[d * D_STATE + s]);
    float h = 0.0f;
    size_t bbase = (size_t)b * SEQ;
    for (int t0 = 0; t0 < SEQ; t0 += 64) {
#pragma unroll
        for (int i = 0; i < 4; i++) {
            int idx = tid + i * 256;
            int tt = idx >> 4, c = idx & 15;
            size_t row = bbase + t0 + tt;
            sdt[tt][c] = DT[row * D_INNER + d0 + c];
            sx[tt][c]  = XC[row * D_INNER + d0 + c];
            sB[tt][c]  = XD[row * 64 + DT_RANK + c];
            sC[tt][c]  = XD[row * 64 + DT_RANK + D_STATE + c];
        }
        __syncthreads();
        for (int tt = 0; tt < 64; tt++) {
            float dtv = sdt[tt][dl];
            float xv  = sx[tt][dl];
            h = __expf(dtv * Av) * h + (dtv * xv) * sB[tt][s];
            float p = h * sC[tt][s];
            p += __shfl_xor(p, 1);
            p += __shfl_xor(p, 2);
            p += __shfl_xor(p, 4);
            p += __shfl_xor(p, 8);
            if (s == 0) DT[(bbase + t0 + tt) * D_INNER + d] = p;
        }
        __syncthreads();
    }
}

// ---------------- combine: y = (y + x*Dskip) * silu(z); also emit bf16 ----------------
__global__ __launch_bounds__(256) void combine_kernel(
    const float* __restrict__ Y, const float* __restrict__ XC,
    const float* __restrict__ XZ, const float* __restrict__ Dskip,
    bf16_t* __restrict__ outb)
{
    size_t gid = (size_t)blockIdx.x * 256 + threadIdx.x;  // over NROWS*D_INNER
    int d = (int)(gid & (D_INNER - 1));
    size_t bt = gid >> 10;
    float z = XZ[bt * (2 * D_INNER) + D_INNER + d];
    float y = Y[gid] + XC[gid] * Dskip[d];
    outb[gid] = (bf16_t)(y * silu(z));
}

// ---------------- launch ----------------

extern "C" void kernel_launch(void* const* d_in, const int* in_sizes, int n_in,
                              void* d_out, int out_size, void* d_ws, size_t ws_size,
                              hipStream_t stream) {
    const int*   src       = (const int*)d_in[0];
    const float* emb_w     = (const float*)d_in[2];
    const float* enc_ln_w  = (const float*)d_in[3];
    const float* enc_ln_b  = (const float*)d_in[4];
    const float* ln_w      = (const float*)d_in[5];
    const float* ln_b      = (const float*)d_in[6];
    const float* in_proj_w = (const float*)d_in[7];
    const float* conv_w    = (const float*)d_in[8];
    const float* conv_b    = (const float*)d_in[9];
    const float* x_proj_w  = (const float*)d_in[10];
    const float* dt_proj_w = (const float*)d_in[11];
    const float* dt_proj_b = (const float*)d_in[12];
    const float* A_log     = (const float*)d_in[13];
    const float* D_skip    = (const float*)d_in[14];
    const float* out_proj_w= (const float*)d_in[15];
    const float* normf_w   = (const float*)d_in[16];
    const float* normf_b   = (const float*)d_in[17];
    float* out = (float*)d_out;

    // fp32 scratch
    float* R  = (float*)d_ws;                     // 8192*512
    float* H  = R  + (size_t)NROWS * D_MODEL;     // 8192*512
    float* XZ = H  + (size_t)NROWS * D_MODEL;     // 8192*2048
    float* XC = XZ + (size_t)NROWS * 2 * D_INNER; // 8192*1024
    float* XD = XC + (size_t)NROWS * D_INNER;     // 8192*64
    float* DT = XD + (size_t)NROWS * 64;          // 8192*1024
    // bf16 scratch (after fp32 region)
    bf16_t* Hb  = (bf16_t*)(DT + (size_t)NROWS * D_INNER);        // 8192*512
    bf16_t* XCb = Hb  + (size_t)NROWS * D_MODEL;                  // 8192*1024
    bf16_t* Wib = XCb + (size_t)NROWS * D_INNER;                  // 4*2048*512
    bf16_t* Wob = Wib + (size_t)NLAYERS * 2 * D_INNER * D_MODEL;  // 4*512*1024

    // cast weights once per launch
    cast_bf16_kernel<<<2048, 256, 0, stream>>>(in_proj_w, Wib, (size_t)NLAYERS * 2 * D_INNER * D_MODEL);
    cast_bf16_kernel<<<2048, 256, 0, stream>>>(out_proj_w, Wob, (size_t)NLAYERS * D_MODEL * D_INNER);

    embed_ln_kernel<<<NROWS, 256, 0, stream>>>(src, emb_w, enc_ln_w, enc_ln_b, R);

    for (int L = 0; L < NLAYERS; L++) {
        // residual add (except layer 0) + LN -> Hb (bf16); H fp32 not needed pre-GEMM
        add_ln_kernel<<<NROWS, 256, 0, stream>>>(
            R, (L == 0) ? nullptr : H, ln_w + L * D_MODEL, ln_b + L * D_MODEL,
            nullptr, Hb);

        // in_proj (bf16 MFMA): Hb(8192x512) x Wib_L(2048x512)^T -> XZ fp32
        gemm_bf16_nt<<<dim3(2 * D_INNER / 128, NROWS / 128), 256, 0, stream>>>(
            Hb, Wib + (size_t)L * 2 * D_INNER * D_MODEL, XZ, 2 * D_INNER, D_MODEL);

        // conv + silu -> XC (fp32) + XCb (bf16)
        conv_silu_kernel<<<(NROWS * D_INNER) / 256, 256, 0, stream>>>(
            XZ, conv_w + (size_t)L * D_INNER * D_CONV, conv_b + (size_t)L * D_INNER, XC, XCb);

        // x_proj (fp32): XC(8192x1024) @ W^T(1024->64) -> XD
        gemm_nt<0><<<dim3(64 / 64, NROWS / 64), 256, 0, stream>>>(
            XC, D_INNER, x_proj_w + (size_t)L * 64 * D_INNER, D_INNER,
            XD, 64, D_INNER, nullptr);

        // dt_proj + softplus (fp32): XD[:, :32] @ W^T(32->1024) + b -> DT
        gemm_nt<1><<<dim3(D_INNER / 64, NROWS / 64), 256, 0, stream>>>(
            XD, 64, dt_proj_w + (size_t)L * D_INNER * DT_RANK, DT_RANK,
            DT, D_INNER, DT_RANK, dt_proj_b + (size_t)L * D_INNER);

        // selective scan (y in-place into DT)
        scan_kernel<<<B_SZ * (D_INNER / 16), 256, 0, stream>>>(
            DT, XC, XD, A_log + (size_t)L * D_INNER * D_STATE);

        // combine -> XCb (bf16 input of out_proj)
        combine_kernel<<<(NROWS * D_INNER) / 256, 256, 0, stream>>>(
            DT, XC, XZ, D_skip + (size_t)L * D_INNER, XCb);

        // out_proj (bf16 MFMA): XCb(8192x1024) x Wob_L(512x1024)^T -> H fp32
        gemm_bf16_nt<<<dim3(D_MODEL / 128, NROWS / 128), 256, 0, stream>>>(
            XCb, Wob + (size_t)L * D_MODEL * D_INNER, H, D_MODEL, D_INNER);
    }

    // final residual add + LN -> out
    add_ln_kernel<<<NROWS, 256, 0, stream>>>(R, H, normf_w, normf_b, out, nullptr);
}

// Round 3
// 1554.997 us; speedup vs baseline: 2.9234x; 1.7832x over previous
//
#include <hip/hip_runtime.h>
#include <hip/hip_bf16.h>
#include <math.h>

#define NTOKEN 60697
#define D_MODEL 512
#define NLAYERS 4
#define D_STATE 16
#define D_CONV 4
#define D_INNER 1024
#define DT_RANK 32
#define B_SZ 4
#define SEQ 2048
#define EPS 1e-5f
#define NROWS (B_SZ * SEQ)   // 8192
#define T_TILE 32

typedef __bf16 bf16_t;
typedef __attribute__((ext_vector_type(8))) __bf16 bfx8;
typedef __attribute__((ext_vector_type(4))) __bf16 bfx4;
typedef __attribute__((ext_vector_type(4))) float f32x4;

// ---------------- utilities ----------------

__device__ __forceinline__ float fast_sigmoid(float x) {
    return 1.0f / (1.0f + __expf(-x));
}
__device__ __forceinline__ float silu(float x) {
    return x * fast_sigmoid(x);
}
__device__ __forceinline__ float softplus_f(float x) {
    return (x > 20.0f) ? x : log1pf(__expf(x));
}

__device__ __forceinline__ void gload_lds16(const void* g, void* l) {
    __builtin_amdgcn_global_load_lds(
        (const __attribute__((address_space(1))) unsigned int*)g,
        (__attribute__((address_space(3))) unsigned int*)l, 16, 0, 0);
}

// DPP fetch: returns value of lane (lane op ctrl) within 16-lane row; VALU pipe.
template <int CTRL>
__device__ __forceinline__ float dpp_fetch(float x) {
    int xi = __builtin_bit_cast(int, x);
    int yi = __builtin_amdgcn_update_dpp(0, xi, CTRL, 0xF, 0xF, true);
    return __builtin_bit_cast(float, yi);
}
// butterfly sum over 16-lane group; result in ALL 16 lanes.
__device__ __forceinline__ float dpp_sum16(float p) {
    p += dpp_fetch<0xB1>(p);   // quad_perm [1,0,3,2]  : xor 1
    p += dpp_fetch<0x4E>(p);   // quad_perm [2,3,0,1]  : xor 2
    p += dpp_fetch<0x141>(p);  // row_half_mirror      : crosses quad within 8
    p += dpp_fetch<0x140>(p);  // row_mirror           : crosses 8 within 16
    return p;
}

// block of 256 threads (4 waves). sbuf must be float[4] shared.
__device__ __forceinline__ float blk_reduce_sum(float x, float* sbuf) {
#pragma unroll
    for (int m = 32; m >= 1; m >>= 1) x += __shfl_xor(x, m);
    int wid = threadIdx.x >> 6;
    if ((threadIdx.x & 63) == 0) sbuf[wid] = x;
    __syncthreads();
    float t = sbuf[0] + sbuf[1] + sbuf[2] + sbuf[3];
    __syncthreads();
    return t;
}

// ---------------- fp32 -> bf16 cast (RNE), vector x4 ----------------
__global__ __launch_bounds__(256) void cast_bf16_kernel(
    const float* __restrict__ in, bf16_t* __restrict__ out, size_t n)
{
    size_t stride = (size_t)gridDim.x * 256 * 4;
    for (size_t i = ((size_t)blockIdx.x * 256 + threadIdx.x) * 4; i < n; i += stride) {
        float4 v = *reinterpret_cast<const float4*>(in + i);
        bfx4 o;
        o[0] = (bf16_t)v.x; o[1] = (bf16_t)v.y;
        o[2] = (bf16_t)v.z; o[3] = (bf16_t)v.w;
        *reinterpret_cast<bfx4*>(out + i) = o;
    }
}

// ---------------- Weff[L][n][k] = sum_r dtw[L][n][r] * xw[L][r][k]  (bf16 out) ----
__global__ __launch_bounds__(256) void weff_kernel(
    const float* __restrict__ dtw, const float* __restrict__ xw,
    bf16_t* __restrict__ Weff)
{
    int L = blockIdx.y;
    int idx = blockIdx.x * 256 + threadIdx.x;   // over 1024*1024
    int n = idx >> 10, k = idx & 1023;
    const float* dtwL = dtw + (size_t)L * D_INNER * DT_RANK;
    const float* xwL  = xw  + (size_t)L * (DT_RANK + 2 * D_STATE) * D_INNER;
    float acc = 0.f;
#pragma unroll
    for (int r = 0; r < DT_RANK; r++)
        acc += dtwL[n * DT_RANK + r] * xwL[r * D_INNER + k];
    Weff[(size_t)L * D_INNER * D_INNER + idx] = (bf16_t)acc;
}

// ---------------- embedding + layernorm ----------------

__global__ __launch_bounds__(256) void embed_ln_kernel(
    const int* __restrict__ src, const float* __restrict__ emb,
    const float* __restrict__ w, const float* __restrict__ b,
    float* __restrict__ R)
{
    __shared__ float sbuf[4];
    int row = blockIdx.x;
    int tok = src[row];
    const float* e = emb + (size_t)tok * D_MODEL;
    int c0 = threadIdx.x, c1 = threadIdx.x + 256;
    float v0 = e[c0], v1 = e[c1];
    float mu = blk_reduce_sum(v0 + v1, sbuf) * (1.0f / D_MODEL);
    float d0 = v0 - mu, d1 = v1 - mu;
    float var = blk_reduce_sum(d0 * d0 + d1 * d1, sbuf) * (1.0f / D_MODEL);
    float rs = rsqrtf(var + EPS);
    size_t base = (size_t)row * D_MODEL;
    R[base + c0] = d0 * rs * w[c0] + b[c0];
    R[base + c1] = d1 * rs * w[c1] + b[c1];
}

// optional residual add (R += Hadd), then LN(R) -> out (fp32) and outb (bf16)
__global__ __launch_bounds__(256) void add_ln_kernel(
    float* __restrict__ R, const float* __restrict__ Hadd,
    const float* __restrict__ w, const float* __restrict__ b,
    float* __restrict__ out, bf16_t* __restrict__ outb)
{
    __shared__ float sbuf[4];
    size_t base = (size_t)blockIdx.x * D_MODEL;
    int c0 = threadIdx.x, c1 = c0 + 256;
    float v0 = R[base + c0], v1 = R[base + c1];
    if (Hadd) {
        v0 += Hadd[base + c0];
        v1 += Hadd[base + c1];
        R[base + c0] = v0;
        R[base + c1] = v1;
    }
    float mu = blk_reduce_sum(v0 + v1, sbuf) * (1.0f / D_MODEL);
    float d0 = v0 - mu, d1 = v1 - mu;
    float var = blk_reduce_sum(d0 * d0 + d1 * d1, sbuf) * (1.0f / D_MODEL);
    float rs = rsqrtf(var + EPS);
    float o0 = d0 * rs * w[c0] + b[c0];
    float o1 = d1 * rs * w[c1] + b[c1];
    if (out) {
        out[base + c0] = o0;
        out[base + c1] = o1;
    }
    if (outb) {
        outb[base + c0] = (bf16_t)o0;
        outb[base + c1] = (bf16_t)o1;
    }
}

// ---------------- bf16 MFMA GEMM (NT): C[m][n] = sum_k A[m][k]*B[n][k] ----------------
// 128x128 tile, BK=32, 256 threads (4 waves 2x2), global_load_lds w16.
// EPI: 0 = plain store, 1 = softplus(v + bias[n])
template <int EPI>
__global__ __launch_bounds__(256) void gemm_bf16_nt(
    const bf16_t* __restrict__ A, const bf16_t* __restrict__ B,
    float* __restrict__ C, int ldc, int K, const float* __restrict__ bias)
{
    __shared__ bf16_t As[128 * 32];
    __shared__ bf16_t Bs[128 * 32];
    int tid = threadIdx.x;
    int lane = tid & 63, wid = tid >> 6;
    int m0 = blockIdx.y * 128, n0 = blockIdx.x * 128;
    int wm = (wid >> 1) * 64, wn = (wid & 1) * 64;
    int c_lo = lane & 15;
    int khalf = lane >> 4;

    f32x4 acc[4][4];
#pragma unroll
    for (int i = 0; i < 4; i++)
#pragma unroll
        for (int j = 0; j < 4; j++)
            acc[i][j] = (f32x4){0.f, 0.f, 0.f, 0.f};

    for (int k0 = 0; k0 < K; k0 += 32) {
#pragma unroll
        for (int i = 0; i < 2; i++) {
            int c = i * 256 + tid;
            int row = c >> 2;
            int cb = (c & 3) * 16;
            int ldsoff = (i * 256 + wid * 64) * 16;
            gload_lds16((const char*)A + ((size_t)(m0 + row) * K + k0) * 2 + cb,
                        (char*)As + ldsoff);
            gload_lds16((const char*)B + ((size_t)(n0 + row) * K + k0) * 2 + cb,
                        (char*)Bs + ldsoff);
        }
        __syncthreads();

        bfx8 af[4], bfr[4];
#pragma unroll
        for (int i = 0; i < 4; i++) {
            af[i]  = *reinterpret_cast<const bfx8*>(As + (wm + i * 16 + c_lo) * 32 + khalf * 8);
            bfr[i] = *reinterpret_cast<const bfx8*>(Bs + (wn + i * 16 + c_lo) * 32 + khalf * 8);
        }
#pragma unroll
        for (int i = 0; i < 4; i++)
#pragma unroll
            for (int j = 0; j < 4; j++)
                acc[i][j] = __builtin_amdgcn_mfma_f32_16x16x32_bf16(af[i], bfr[j], acc[i][j], 0, 0, 0);
        __syncthreads();
    }

#pragma unroll
    for (int i = 0; i < 4; i++) {
#pragma unroll
        for (int j = 0; j < 4; j++) {
            int row0 = m0 + wm + i * 16 + khalf * 4;
            int col = n0 + wn + j * 16 + c_lo;
#pragma unroll
            for (int r = 0; r < 4; r++) {
                float v = acc[i][j][r];
                if (EPI == 1) v = softplus_f(v + bias[col]);
                C[(size_t)(row0 + r) * ldc + col] = v;
            }
        }
    }
}

// ---------------- skinny bf16 MFMA GEMM: BC = XCb @ Bmat^T, N=32 ----------------
// tile 64 rows x 32 cols, 128 threads (2 waves, 32 rows each), BK=32.
__global__ __launch_bounds__(128) void gemm_bc_bf16(
    const bf16_t* __restrict__ A, const bf16_t* __restrict__ Bmat,
    float* __restrict__ C, int K)
{
    __shared__ bf16_t As[64 * 32];
    __shared__ bf16_t Bs[32 * 32];
    int tid = threadIdx.x;
    int lane = tid & 63, w = tid >> 6;
    int m0 = blockIdx.x * 64;
    int wr0 = w * 32;
    int c_lo = lane & 15;
    int khalf = lane >> 4;

    f32x4 acc[2][2];
#pragma unroll
    for (int i = 0; i < 2; i++)
#pragma unroll
        for (int j = 0; j < 2; j++)
            acc[i][j] = (f32x4){0.f, 0.f, 0.f, 0.f};

    for (int k0 = 0; k0 < K; k0 += 32) {
        // As: 64 rows x 64B = 256 chunks; Bs: 128 chunks
        {
            int c = tid;               // As chunks 0..127
            gload_lds16((const char*)A + ((size_t)(m0 + (c >> 2)) * K + k0) * 2 + (c & 3) * 16,
                        (char*)As + w * 1024);
        }
        {
            int c = tid + 128;         // As chunks 128..255
            gload_lds16((const char*)A + ((size_t)(m0 + (c >> 2)) * K + k0) * 2 + (c & 3) * 16,
                        (char*)As + 2048 + w * 1024);
        }
        {
            int c = tid;               // Bs chunks 0..127
            gload_lds16((const char*)Bmat + ((size_t)(c >> 2) * K + k0) * 2 + (c & 3) * 16,
                        (char*)Bs + w * 1024);
        }
        __syncthreads();

        bfx8 af[2], bfr[2];
#pragma unroll
        for (int i = 0; i < 2; i++)
            af[i] = *reinterpret_cast<const bfx8*>(As + (wr0 + i * 16 + c_lo) * 32 + khalf * 8);
#pragma unroll
        for (int j = 0; j < 2; j++)
            bfr[j] = *reinterpret_cast<const bfx8*>(Bs + (j * 16 + c_lo) * 32 + khalf * 8);
#pragma unroll
        for (int i = 0; i < 2; i++)
#pragma unroll
            for (int j = 0; j < 2; j++)
                acc[i][j] = __builtin_amdgcn_mfma_f32_16x16x32_bf16(af[i], bfr[j], acc[i][j], 0, 0, 0);
        __syncthreads();
    }

#pragma unroll
    for (int i = 0; i < 2; i++)
#pragma unroll
        for (int j = 0; j < 2; j++) {
            int row0 = m0 + wr0 + i * 16 + khalf * 4;
            int col = j * 16 + c_lo;
#pragma unroll
            for (int r = 0; r < 4; r++)
                C[(size_t)(row0 + r) * 32 + col] = acc[i][j][r];
        }
}

// ---------------- causal depthwise conv + silu ----------------
__global__ __launch_bounds__(256) void conv_silu_kernel(
    const float* __restrict__ XZ, const float* __restrict__ cw,
    const float* __restrict__ cb, float* __restrict__ XC, bf16_t* __restrict__ XCb)
{
    size_t gid = (size_t)blockIdx.x * 256 + threadIdx.x;
    int d = (int)(gid & (D_INNER - 1));
    size_t bt = gid >> 10;
    int t = (int)(bt & (SEQ - 1));
    float acc = cb[d];
#pragma unroll
    for (int k = 0; k < D_CONV; k++) {
        int tt = t + k - (D_CONV - 1);
        if (tt >= 0)
            acc += cw[d * D_CONV + k] * XZ[(bt + (size_t)(k - (D_CONV - 1))) * (2 * D_INNER) + d];
    }
    float v = silu(acc);
    XC[gid] = v;
    XCb[gid] = (bf16_t)v;
}

// ---------------- selective scan v2 ----------------
// block: 16 ch x 16 states; grid B_SZ * 64. Double-buffered global_load_lds
// staging of 32-step tiles; DPP butterfly reduce; deferred coalesced stores.
__global__ __launch_bounds__(256) void scan2_kernel(
    float* __restrict__ DT, const float* __restrict__ XC,
    const float* __restrict__ BC, const float* __restrict__ A_log)
{
    // slot layout (floats): dt [0,512), x [512,1024), bc [1024,2048)
    __shared__ float lds[2][2048];
    const int tid = threadIdx.x;
    const int w = tid >> 6;
    const int s = tid & 15, dl = tid >> 4;
    const int b = blockIdx.x >> 6;
    const int d0 = (blockIdx.x & 63) * 16;
    const float Av = -__expf(A_log[(d0 + dl) * D_STATE + s]);
    float h = 0.f;
    const size_t bbase = (size_t)b * SEQ;

    // --- staging: 512 chunks of 16B per tile; 2 gload_lds per thread ---
    auto stage = [&](int slot, int t0) {
        float* base = lds[slot];
        size_t rowbase = bbase + t0;
        {   // chunks c = tid: dt (c<128) else x
            int c = tid;
            const float* g;
            if (c < 128) g = DT + (rowbase + (c >> 2)) * (size_t)D_INNER + d0 + (c & 3) * 4;
            else { int cc = c - 128; g = XC + (rowbase + (cc >> 2)) * (size_t)D_INNER + d0 + (cc & 3) * 4; }
            gload_lds16(g, (char*)base + w * 1024);
        }
        {   // chunks 256 + tid: bc
            int cc = tid;
            const float* g = BC + (rowbase + (cc >> 3)) * 32 + (cc & 7) * 4;
            gload_lds16(g, (char*)base + 4096 + w * 1024);
        }
    };

    stage(0, 0);
    __syncthreads();
    int cur = 0;
    for (int t0 = 0; t0 < SEQ; t0 += T_TILE) {
        if (t0 + T_TILE < SEQ) stage(cur ^ 1, t0 + T_TILE);
        const float* Ldt = lds[cur];
        const float* Lx  = lds[cur] + 512;
        const float* Lbc = lds[cur] + 1024;
        float yhold = 0.f;
#pragma unroll
        for (int k = 0; k < T_TILE; k++) {
            float dtv = Ldt[k * 16 + dl];
            float xv  = Lx [k * 16 + dl];
            float bv  = Lbc[k * 32 + s];
            float cv  = Lbc[k * 32 + 16 + s];
            float dA = __expf(dtv * Av);
            h = fmaf(dA, h, dtv * xv * bv);
            float p = dpp_sum16(h * cv);
            if (s == (k & 15)) yhold = p;
            if ((k & 15) == 15) {
                int t = t0 + (k & 16) + s;
                DT[(bbase + t) * (size_t)D_INNER + d0 + dl] = yhold;
            }
        }
        __syncthreads();
        cur ^= 1;
    }
}

// ---------------- combine: y = (y + x*Dskip) * silu(z); emit bf16 ----------------
__global__ __launch_bounds__(256) void combine_kernel(
    const float* __restrict__ Y, const float* __restrict__ XC,
    const float* __restrict__ XZ, const float* __restrict__ Dskip,
    bf16_t* __restrict__ outb)
{
    size_t gid = (size_t)blockIdx.x * 256 + threadIdx.x;
    int d = (int)(gid & (D_INNER - 1));
    size_t bt = gid >> 10;
    float z = XZ[bt * (2 * D_INNER) + D_INNER + d];
    float y = Y[gid] + XC[gid] * Dskip[d];
    outb[gid] = (bf16_t)(y * silu(z));
}

// ---------------- launch ----------------

extern "C" void kernel_launch(void* const* d_in, const int* in_sizes, int n_in,
                              void* d_out, int out_size, void* d_ws, size_t ws_size,
                              hipStream_t stream) {
    const int*   src       = (const int*)d_in[0];
    const float* emb_w     = (const float*)d_in[2];
    const float* enc_ln_w  = (const float*)d_in[3];
    const float* enc_ln_b  = (const float*)d_in[4];
    const float* ln_w      = (const float*)d_in[5];
    const float* ln_b      = (const float*)d_in[6];
    const float* in_proj_w = (const float*)d_in[7];
    const float* conv_w    = (const float*)d_in[8];
    const float* conv_b    = (const float*)d_in[9];
    const float* x_proj_w  = (const float*)d_in[10];
    const float* dt_proj_w = (const float*)d_in[11];
    const float* dt_proj_b = (const float*)d_in[12];
    const float* A_log     = (const float*)d_in[13];
    const float* D_skip    = (const float*)d_in[14];
    const float* out_proj_w= (const float*)d_in[15];
    const float* normf_w   = (const float*)d_in[16];
    const float* normf_b   = (const float*)d_in[17];
    float* out = (float*)d_out;

    // fp32 scratch
    float* R   = (float*)d_ws;                      // 8192*512
    float* H   = R   + (size_t)NROWS * D_MODEL;     // 8192*512
    float* XZ  = H   + (size_t)NROWS * D_MODEL;     // 8192*2048
    float* XC  = XZ  + (size_t)NROWS * 2 * D_INNER; // 8192*1024
    float* BCf = XC  + (size_t)NROWS * D_INNER;     // 8192*32
    float* DT  = BCf + (size_t)NROWS * 32;          // 8192*1024
    // bf16 scratch
    bf16_t* Hb    = (bf16_t*)(DT + (size_t)NROWS * D_INNER);
    bf16_t* XCb   = Hb    + (size_t)NROWS * D_MODEL;
    bf16_t* Wib   = XCb   + (size_t)NROWS * D_INNER;                   // 4*2048*512
    bf16_t* Wob   = Wib   + (size_t)NLAYERS * 2 * D_INNER * D_MODEL;   // 4*512*1024
    bf16_t* Weffb = Wob   + (size_t)NLAYERS * D_MODEL * D_INNER;       // 4*1024*1024
    bf16_t* xpb   = Weffb + (size_t)NLAYERS * D_INNER * D_INNER;       // 4*64*1024

    // one-time (per launch) weight prep
    cast_bf16_kernel<<<2048, 256, 0, stream>>>(in_proj_w, Wib, (size_t)NLAYERS * 2 * D_INNER * D_MODEL);
    cast_bf16_kernel<<<2048, 256, 0, stream>>>(out_proj_w, Wob, (size_t)NLAYERS * D_MODEL * D_INNER);
    cast_bf16_kernel<<<256, 256, 0, stream>>>(x_proj_w, xpb, (size_t)NLAYERS * (DT_RANK + 2 * D_STATE) * D_INNER);
    weff_kernel<<<dim3(4096, NLAYERS), 256, 0, stream>>>(dt_proj_w, x_proj_w, Weffb);

    embed_ln_kernel<<<NROWS, 256, 0, stream>>>(src, emb_w, enc_ln_w, enc_ln_b, R);

    for (int L = 0; L < NLAYERS; L++) {
        add_ln_kernel<<<NROWS, 256, 0, stream>>>(
            R, (L == 0) ? nullptr : H, ln_w + L * D_MODEL, ln_b + L * D_MODEL,
            nullptr, Hb);

        // in_proj: Hb(8192x512) x Wib_L(2048x512)^T -> XZ fp32
        gemm_bf16_nt<0><<<dim3(2 * D_INNER / 128, NROWS / 128), 256, 0, stream>>>(
            Hb, Wib + (size_t)L * 2 * D_INNER * D_MODEL, XZ, 2 * D_INNER, D_MODEL, nullptr);

        conv_silu_kernel<<<(NROWS * D_INNER) / 256, 256, 0, stream>>>(
            XZ, conv_w + (size_t)L * D_INNER * D_CONV, conv_b + (size_t)L * D_INNER, XC, XCb);

        // B,C: XCb(8192x1024) x xw[32:64]^T -> BCf fp32 (8192x32)
        gemm_bc_bf16<<<NROWS / 64, 128, 0, stream>>>(
            XCb, xpb + (size_t)L * 64 * D_INNER + (size_t)DT_RANK * D_INNER, BCf, D_INNER);

        // dt: softplus(XCb x Weff_L^T + dtb) -> DT fp32 (8192x1024)
        gemm_bf16_nt<1><<<dim3(D_INNER / 128, NROWS / 128), 256, 0, stream>>>(
            XCb, Weffb + (size_t)L * D_INNER * D_INNER, DT, D_INNER, D_INNER,
            dt_proj_b + (size_t)L * D_INNER);

        // selective scan (y in-place into DT)
        scan2_kernel<<<B_SZ * (D_INNER / 16), 256, 0, stream>>>(
            DT, XC, BCf, A_log + (size_t)L * D_INNER * D_STATE);

        combine_kernel<<<(NROWS * D_INNER) / 256, 256, 0, stream>>>(
            DT, XC, XZ, D_skip + (size_t)L * D_INNER, XCb);

        // out_proj: XCb(8192x1024) x Wob_L(512x1024)^T -> H fp32
        gemm_bf16_nt<0><<<dim3(D_MODEL / 128, NROWS / 128), 256, 0, stream>>>(
            XCb, Wob + (size_t)L * D_MODEL * D_INNER, H, D_MODEL, D_INNER, nullptr);
    }

    add_ln_kernel<<<NROWS, 256, 0, stream>>>(R, H, normf_w, normf_b, out, nullptr);
}

// Round 4
// 1397.687 us; speedup vs baseline: 3.2524x; 1.1126x over previous
//
#include <hip/hip_runtime.h>
#include <hip/hip_bf16.h>
#include <math.h>

#define NTOKEN 60697
#define D_MODEL 512
#define NLAYERS 4
#define D_STATE 16
#define D_CONV 4
#define D_INNER 1024
#define DT_RANK 32
#define B_SZ 4
#define SEQ 2048
#define EPS 1e-5f
#define NROWS (B_SZ * SEQ)   // 8192
#define T_TILE 32

typedef __bf16 bf16_t;
typedef __attribute__((ext_vector_type(8))) __bf16 bfx8;
typedef __attribute__((ext_vector_type(4))) __bf16 bfx4;
typedef __attribute__((ext_vector_type(4))) float f32x4;

// ---------------- utilities ----------------

__device__ __forceinline__ float fast_sigmoid(float x) {
    return 1.0f / (1.0f + __expf(-x));
}
__device__ __forceinline__ float silu(float x) {
    return x * fast_sigmoid(x);
}
__device__ __forceinline__ float softplus_f(float x) {
    return (x > 20.0f) ? x : log1pf(__expf(x));
}

__device__ __forceinline__ void gload_lds16(const void* g, void* l) {
    __builtin_amdgcn_global_load_lds(
        (const __attribute__((address_space(1))) unsigned int*)g,
        (__attribute__((address_space(3))) unsigned int*)l, 16, 0, 0);
}

// DPP fetch: returns value of lane (lane op ctrl) within 16-lane row; VALU pipe.
template <int CTRL>
__device__ __forceinline__ float dpp_fetch(float x) {
    int xi = __builtin_bit_cast(int, x);
    int yi = __builtin_amdgcn_update_dpp(0, xi, CTRL, 0xF, 0xF, true);
    return __builtin_bit_cast(float, yi);
}
// butterfly sum over 16-lane group; result in ALL 16 lanes.
__device__ __forceinline__ float dpp_sum16(float p) {
    p += dpp_fetch<0xB1>(p);   // quad_perm [1,0,3,2]  : xor 1
    p += dpp_fetch<0x4E>(p);   // quad_perm [2,3,0,1]  : xor 2
    p += dpp_fetch<0x141>(p);  // row_half_mirror      : crosses quad within 8
    p += dpp_fetch<0x140>(p);  // row_mirror           : crosses 8 within 16
    return p;
}

// block of 256 threads (4 waves). sbuf must be float[4] shared.
__device__ __forceinline__ float blk_reduce_sum(float x, float* sbuf) {
#pragma unroll
    for (int m = 32; m >= 1; m >>= 1) x += __shfl_xor(x, m);
    int wid = threadIdx.x >> 6;
    if ((threadIdx.x & 63) == 0) sbuf[wid] = x;
    __syncthreads();
    float t = sbuf[0] + sbuf[1] + sbuf[2] + sbuf[3];
    __syncthreads();
    return t;
}

// ---------------- fp32 -> bf16 cast (RNE), vector x4 ----------------
__global__ __launch_bounds__(256) void cast_bf16_kernel(
    const float* __restrict__ in, bf16_t* __restrict__ out, size_t n)
{
    size_t stride = (size_t)gridDim.x * 256 * 4;
    for (size_t i = ((size_t)blockIdx.x * 256 + threadIdx.x) * 4; i < n; i += stride) {
        float4 v = *reinterpret_cast<const float4*>(in + i);
        bfx4 o;
        o[0] = (bf16_t)v.x; o[1] = (bf16_t)v.y;
        o[2] = (bf16_t)v.z; o[3] = (bf16_t)v.w;
        *reinterpret_cast<bfx4*>(out + i) = o;
    }
}

// ---------------- Weff[L][n][k] = sum_r dtw[L][n][r] * xw[L][r][k]  (bf16 out) ----
__global__ __launch_bounds__(256) void weff_kernel(
    const float* __restrict__ dtw, const float* __restrict__ xw,
    bf16_t* __restrict__ Weff)
{
    int L = blockIdx.y;
    int idx = blockIdx.x * 256 + threadIdx.x;   // over 1024*1024
    int n = idx >> 10, k = idx & 1023;
    const float* dtwL = dtw + (size_t)L * D_INNER * DT_RANK;
    const float* xwL  = xw  + (size_t)L * (DT_RANK + 2 * D_STATE) * D_INNER;
    float acc = 0.f;
#pragma unroll
    for (int r = 0; r < DT_RANK; r++)
        acc += dtwL[n * DT_RANK + r] * xwL[r * D_INNER + k];
    Weff[(size_t)L * D_INNER * D_INNER + idx] = (bf16_t)acc;
}

// ---------------- embedding + layernorm ----------------

__global__ __launch_bounds__(256) void embed_ln_kernel(
    const int* __restrict__ src, const float* __restrict__ emb,
    const float* __restrict__ w, const float* __restrict__ b,
    float* __restrict__ R)
{
    __shared__ float sbuf[4];
    int row = blockIdx.x;
    int tok = src[row];
    const float* e = emb + (size_t)tok * D_MODEL;
    int c0 = threadIdx.x, c1 = threadIdx.x + 256;
    float v0 = e[c0], v1 = e[c1];
    float mu = blk_reduce_sum(v0 + v1, sbuf) * (1.0f / D_MODEL);
    float d0 = v0 - mu, d1 = v1 - mu;
    float var = blk_reduce_sum(d0 * d0 + d1 * d1, sbuf) * (1.0f / D_MODEL);
    float rs = rsqrtf(var + EPS);
    size_t base = (size_t)row * D_MODEL;
    R[base + c0] = d0 * rs * w[c0] + b[c0];
    R[base + c1] = d1 * rs * w[c1] + b[c1];
}

// optional residual add (R += Hadd), then LN(R) -> out (fp32) and outb (bf16)
__global__ __launch_bounds__(256) void add_ln_kernel(
    float* __restrict__ R, const float* __restrict__ Hadd,
    const float* __restrict__ w, const float* __restrict__ b,
    float* __restrict__ out, bf16_t* __restrict__ outb)
{
    __shared__ float sbuf[4];
    size_t base = (size_t)blockIdx.x * D_MODEL;
    int c0 = threadIdx.x, c1 = c0 + 256;
    float v0 = R[base + c0], v1 = R[base + c1];
    if (Hadd) {
        v0 += Hadd[base + c0];
        v1 += Hadd[base + c1];
        R[base + c0] = v0;
        R[base + c1] = v1;
    }
    float mu = blk_reduce_sum(v0 + v1, sbuf) * (1.0f / D_MODEL);
    float d0 = v0 - mu, d1 = v1 - mu;
    float var = blk_reduce_sum(d0 * d0 + d1 * d1, sbuf) * (1.0f / D_MODEL);
    float rs = rsqrtf(var + EPS);
    float o0 = d0 * rs * w[c0] + b[c0];
    float o1 = d1 * rs * w[c1] + b[c1];
    if (out) {
        out[base + c0] = o0;
        out[base + c1] = o1;
    }
    if (outb) {
        outb[base + c0] = (bf16_t)o0;
        outb[base + c1] = (bf16_t)o1;
    }
}

// ---------------- bf16 MFMA GEMM (NT): C[m][n] = sum_k A[m][k]*B[n][k] ----------------
// 128x128 tile, BK=32, 256 threads (4 waves 2x2), global_load_lds w16.
// EPI: 0 = plain store, 1 = softplus(v + bias[n])
template <int EPI>
__global__ __launch_bounds__(256) void gemm_bf16_nt(
    const bf16_t* __restrict__ A, const bf16_t* __restrict__ B,
    float* __restrict__ C, int ldc, int K, const float* __restrict__ bias)
{
    __shared__ bf16_t As[128 * 32];
    __shared__ bf16_t Bs[128 * 32];
    int tid = threadIdx.x;
    int lane = tid & 63, wid = tid >> 6;
    int m0 = blockIdx.y * 128, n0 = blockIdx.x * 128;
    int wm = (wid >> 1) * 64, wn = (wid & 1) * 64;
    int c_lo = lane & 15;
    int khalf = lane >> 4;

    f32x4 acc[4][4];
#pragma unroll
    for (int i = 0; i < 4; i++)
#pragma unroll
        for (int j = 0; j < 4; j++)
            acc[i][j] = (f32x4){0.f, 0.f, 0.f, 0.f};

    for (int k0 = 0; k0 < K; k0 += 32) {
#pragma unroll
        for (int i = 0; i < 2; i++) {
            int c = i * 256 + tid;
            int row = c >> 2;
            int cb = (c & 3) * 16;
            int ldsoff = (i * 256 + wid * 64) * 16;
            gload_lds16((const char*)A + ((size_t)(m0 + row) * K + k0) * 2 + cb,
                        (char*)As + ldsoff);
            gload_lds16((const char*)B + ((size_t)(n0 + row) * K + k0) * 2 + cb,
                        (char*)Bs + ldsoff);
        }
        __syncthreads();

        bfx8 af[4], bfr[4];
#pragma unroll
        for (int i = 0; i < 4; i++) {
            af[i]  = *reinterpret_cast<const bfx8*>(As + (wm + i * 16 + c_lo) * 32 + khalf * 8);
            bfr[i] = *reinterpret_cast<const bfx8*>(Bs + (wn + i * 16 + c_lo) * 32 + khalf * 8);
        }
#pragma unroll
        for (int i = 0; i < 4; i++)
#pragma unroll
            for (int j = 0; j < 4; j++)
                acc[i][j] = __builtin_amdgcn_mfma_f32_16x16x32_bf16(af[i], bfr[j], acc[i][j], 0, 0, 0);
        __syncthreads();
    }

#pragma unroll
    for (int i = 0; i < 4; i++) {
#pragma unroll
        for (int j = 0; j < 4; j++) {
            int row0 = m0 + wm + i * 16 + khalf * 4;
            int col = n0 + wn + j * 16 + c_lo;
#pragma unroll
            for (int r = 0; r < 4; r++) {
                float v = acc[i][j][r];
                if (EPI == 1) v = softplus_f(v + bias[col]);
                C[(size_t)(row0 + r) * ldc + col] = v;
            }
        }
    }
}

// ---------------- skinny bf16 MFMA GEMM: BC = XCb @ Bmat^T, N=32 ----------------
__global__ __launch_bounds__(128) void gemm_bc_bf16(
    const bf16_t* __restrict__ A, const bf16_t* __restrict__ Bmat,
    float* __restrict__ C, int K)
{
    __shared__ bf16_t As[64 * 32];
    __shared__ bf16_t Bs[32 * 32];
    int tid = threadIdx.x;
    int lane = tid & 63, w = tid >> 6;
    int m0 = blockIdx.x * 64;
    int wr0 = w * 32;
    int c_lo = lane & 15;
    int khalf = lane >> 4;

    f32x4 acc[2][2];
#pragma unroll
    for (int i = 0; i < 2; i++)
#pragma unroll
        for (int j = 0; j < 2; j++)
            acc[i][j] = (f32x4){0.f, 0.f, 0.f, 0.f};

    for (int k0 = 0; k0 < K; k0 += 32) {
        {
            int c = tid;
            gload_lds16((const char*)A + ((size_t)(m0 + (c >> 2)) * K + k0) * 2 + (c & 3) * 16,
                        (char*)As + w * 1024);
        }
        {
            int c = tid + 128;
            gload_lds16((const char*)A + ((size_t)(m0 + (c >> 2)) * K + k0) * 2 + (c & 3) * 16,
                        (char*)As + 2048 + w * 1024);
        }
        {
            int c = tid;
            gload_lds16((const char*)Bmat + ((size_t)(c >> 2) * K + k0) * 2 + (c & 3) * 16,
                        (char*)Bs + w * 1024);
        }
        __syncthreads();

        bfx8 af[2], bfr[2];
#pragma unroll
        for (int i = 0; i < 2; i++)
            af[i] = *reinterpret_cast<const bfx8*>(As + (wr0 + i * 16 + c_lo) * 32 + khalf * 8);
#pragma unroll
        for (int j = 0; j < 2; j++)
            bfr[j] = *reinterpret_cast<const bfx8*>(Bs + (j * 16 + c_lo) * 32 + khalf * 8);
#pragma unroll
        for (int i = 0; i < 2; i++)
#pragma unroll
            for (int j = 0; j < 2; j++)
                acc[i][j] = __builtin_amdgcn_mfma_f32_16x16x32_bf16(af[i], bfr[j], acc[i][j], 0, 0, 0);
        __syncthreads();
    }

#pragma unroll
    for (int i = 0; i < 2; i++)
#pragma unroll
        for (int j = 0; j < 2; j++) {
            int row0 = m0 + wr0 + i * 16 + khalf * 4;
            int col = j * 16 + c_lo;
#pragma unroll
            for (int r = 0; r < 4; r++)
                C[(size_t)(row0 + r) * 32 + col] = acc[i][j][r];
        }
}

// ---------------- causal depthwise conv + silu ----------------
__global__ __launch_bounds__(256) void conv_silu_kernel(
    const float* __restrict__ XZ, const float* __restrict__ cw,
    const float* __restrict__ cb, float* __restrict__ XC, bf16_t* __restrict__ XCb)
{
    size_t gid = (size_t)blockIdx.x * 256 + threadIdx.x;
    int d = (int)(gid & (D_INNER - 1));
    size_t bt = gid >> 10;
    int t = (int)(bt & (SEQ - 1));
    float acc = cb[d];
#pragma unroll
    for (int k = 0; k < D_CONV; k++) {
        int tt = t + k - (D_CONV - 1);
        if (tt >= 0)
            acc += cw[d * D_CONV + k] * XZ[(bt + (size_t)(k - (D_CONV - 1))) * (2 * D_INNER) + d];
    }
    float v = silu(acc);
    XC[gid] = v;
    XCb[gid] = (bf16_t)v;
}

// ---------------- selective scan v3 ----------------
// block: 16 ch x 16 states; grid B_SZ * 64. Double-buffered global_load_lds
// staging; per-16-step phase A hoists LDS reads + exp + u off the serial chain
// into unrolled register arrays; phase B is the fma chain + DPP reduce.
__global__ __launch_bounds__(256) void scan3_kernel(
    float* __restrict__ DT, const float* __restrict__ XC,
    const float* __restrict__ BC, const float* __restrict__ A_log)
{
    // slot layout (floats): dt [0,512), x [512,1024), bc [1024,2048)
    __shared__ float lds[2][2048];
    const int tid = threadIdx.x;
    const int w = tid >> 6;
    const int s = tid & 15, dl = tid >> 4;
    const int b = blockIdx.x >> 6;
    const int d0 = (blockIdx.x & 63) * 16;
    const float Av = -__expf(A_log[(d0 + dl) * D_STATE + s]);
    float h = 0.f;
    const size_t bbase = (size_t)b * SEQ;

    auto stage = [&](int slot, int t0) {
        float* base = lds[slot];
        size_t rowbase = bbase + t0;
        {   // chunks c = tid: dt (c<128) else x
            int c = tid;
            const float* g;
            if (c < 128) g = DT + (rowbase + (c >> 2)) * (size_t)D_INNER + d0 + (c & 3) * 4;
            else { int cc = c - 128; g = XC + (rowbase + (cc >> 2)) * (size_t)D_INNER + d0 + (cc & 3) * 4; }
            gload_lds16(g, (char*)base + w * 1024);
        }
        {   // chunks 256 + tid: bc
            int cc = tid;
            const float* g = BC + (rowbase + (cc >> 3)) * 32 + (cc & 7) * 4;
            gload_lds16(g, (char*)base + 4096 + w * 1024);
        }
    };

    stage(0, 0);
    __syncthreads();
    int cur = 0;
    for (int t0 = 0; t0 < SEQ; t0 += T_TILE) {
        if (t0 + T_TILE < SEQ) stage(cur ^ 1, t0 + T_TILE);
        const float* Ldt = lds[cur];
        const float* Lx  = lds[cur] + 512;
        const float* Lbc = lds[cur] + 1024;
#pragma unroll
        for (int half = 0; half < 2; half++) {
            // ---- phase A: off-chain precompute (unrolled reg arrays) ----
            float e[16], u[16], cv[16];
#pragma unroll
            for (int k = 0; k < 16; k++) {
                int kk = half * 16 + k;
                float dtv = Ldt[kk * 16 + dl];
                float xv  = Lx [kk * 16 + dl];
                float bv  = Lbc[kk * 32 + s];
                cv[k] = Lbc[kk * 32 + 16 + s];
                e[k] = __expf(dtv * Av);
                u[k] = dtv * xv * bv;
            }
            // ---- phase B: serial fma chain + off-chain DPP reduce ----
            float yhold = 0.f;
#pragma unroll
            for (int k = 0; k < 16; k++) {
                h = fmaf(e[k], h, u[k]);
                float p = dpp_sum16(h * cv[k]);
                if (s == k) yhold = p;
            }
            // lane s holds y(t = t0 + half*16 + s) for channel d0+dl
            DT[(bbase + t0 + half * 16 + s) * (size_t)D_INNER + d0 + dl] = yhold;
        }
        __syncthreads();
        cur ^= 1;
    }
}

// ---------------- combine: y = (y + x*Dskip) * silu(z); emit bf16 ----------------
__global__ __launch_bounds__(256) void combine_kernel(
    const float* __restrict__ Y, const float* __restrict__ XC,
    const float* __restrict__ XZ, const float* __restrict__ Dskip,
    bf16_t* __restrict__ outb)
{
    size_t gid = (size_t)blockIdx.x * 256 + threadIdx.x;
    int d = (int)(gid & (D_INNER - 1));
    size_t bt = gid >> 10;
    float z = XZ[bt * (2 * D_INNER) + D_INNER + d];
    float y = Y[gid] + XC[gid] * Dskip[d];
    outb[gid] = (bf16_t)(y * silu(z));
}

// ---------------- launch ----------------

extern "C" void kernel_launch(void* const* d_in, const int* in_sizes, int n_in,
                              void* d_out, int out_size, void* d_ws, size_t ws_size,
                              hipStream_t stream) {
    const int*   src       = (const int*)d_in[0];
    const float* emb_w     = (const float*)d_in[2];
    const float* enc_ln_w  = (const float*)d_in[3];
    const float* enc_ln_b  = (const float*)d_in[4];
    const float* ln_w      = (const float*)d_in[5];
    const float* ln_b      = (const float*)d_in[6];
    const float* in_proj_w = (const float*)d_in[7];
    const float* conv_w    = (const float*)d_in[8];
    const float* conv_b    = (const float*)d_in[9];
    const float* x_proj_w  = (const float*)d_in[10];
    const float* dt_proj_w = (const float*)d_in[11];
    const float* dt_proj_b = (const float*)d_in[12];
    const float* A_log     = (const float*)d_in[13];
    const float* D_skip    = (const float*)d_in[14];
    const float* out_proj_w= (const float*)d_in[15];
    const float* normf_w   = (const float*)d_in[16];
    const float* normf_b   = (const float*)d_in[17];
    float* out = (float*)d_out;

    // fp32 scratch
    float* R   = (float*)d_ws;                      // 8192*512
    float* H   = R   + (size_t)NROWS * D_MODEL;     // 8192*512
    float* XZ  = H   + (size_t)NROWS * D_MODEL;     // 8192*2048
    float* XC  = XZ  + (size_t)NROWS * 2 * D_INNER; // 8192*1024
    float* BCf = XC  + (size_t)NROWS * D_INNER;     // 8192*32
    float* DT  = BCf + (size_t)NROWS * 32;          // 8192*1024
    // bf16 scratch
    bf16_t* Hb    = (bf16_t*)(DT + (size_t)NROWS * D_INNER);
    bf16_t* XCb   = Hb    + (size_t)NROWS * D_MODEL;
    bf16_t* Wib   = XCb   + (size_t)NROWS * D_INNER;                   // 4*2048*512
    bf16_t* Wob   = Wib   + (size_t)NLAYERS * 2 * D_INNER * D_MODEL;   // 4*512*1024
    bf16_t* Weffb = Wob   + (size_t)NLAYERS * D_MODEL * D_INNER;       // 4*1024*1024
    bf16_t* xpb   = Weffb + (size_t)NLAYERS * D_INNER * D_INNER;       // 4*64*1024

    // one-time (per launch) weight prep
    cast_bf16_kernel<<<2048, 256, 0, stream>>>(in_proj_w, Wib, (size_t)NLAYERS * 2 * D_INNER * D_MODEL);
    cast_bf16_kernel<<<2048, 256, 0, stream>>>(out_proj_w, Wob, (size_t)NLAYERS * D_MODEL * D_INNER);
    cast_bf16_kernel<<<256, 256, 0, stream>>>(x_proj_w, xpb, (size_t)NLAYERS * (DT_RANK + 2 * D_STATE) * D_INNER);
    weff_kernel<<<dim3(4096, NLAYERS), 256, 0, stream>>>(dt_proj_w, x_proj_w, Weffb);

    embed_ln_kernel<<<NROWS, 256, 0, stream>>>(src, emb_w, enc_ln_w, enc_ln_b, R);

    for (int L = 0; L < NLAYERS; L++) {
        add_ln_kernel<<<NROWS, 256, 0, stream>>>(
            R, (L == 0) ? nullptr : H, ln_w + L * D_MODEL, ln_b + L * D_MODEL,
            nullptr, Hb);

        // in_proj: Hb(8192x512) x Wib_L(2048x512)^T -> XZ fp32
        gemm_bf16_nt<0><<<dim3(2 * D_INNER / 128, NROWS / 128), 256, 0, stream>>>(
            Hb, Wib + (size_t)L * 2 * D_INNER * D_MODEL, XZ, 2 * D_INNER, D_MODEL, nullptr);

        conv_silu_kernel<<<(NROWS * D_INNER) / 256, 256, 0, stream>>>(
            XZ, conv_w + (size_t)L * D_INNER * D_CONV, conv_b + (size_t)L * D_INNER, XC, XCb);

        // B,C: XCb(8192x1024) x xw[32:64]^T -> BCf fp32 (8192x32)
        gemm_bc_bf16<<<NROWS / 64, 128, 0, stream>>>(
            XCb, xpb + (size_t)L * 64 * D_INNER + (size_t)DT_RANK * D_INNER, BCf, D_INNER);

        // dt: softplus(XCb x Weff_L^T + dtb) -> DT fp32 (8192x1024)
        gemm_bf16_nt<1><<<dim3(D_INNER / 128, NROWS / 128), 256, 0, stream>>>(
            XCb, Weffb + (size_t)L * D_INNER * D_INNER, DT, D_INNER, D_INNER,
            dt_proj_b + (size_t)L * D_INNER);

        // selective scan (y in-place into DT)
        scan3_kernel<<<B_SZ * (D_INNER / 16), 256, 0, stream>>>(
            DT, XC, BCf, A_log + (size_t)L * D_INNER * D_STATE);

        combine_kernel<<<(NROWS * D_INNER) / 256, 256, 0, stream>>>(
            DT, XC, XZ, D_skip + (size_t)L * D_INNER, XCb);

        // out_proj: XCb(8192x1024) x Wob_L(512x1024)^T -> H fp32
        gemm_bf16_nt<0><<<dim3(D_MODEL / 128, NROWS / 128), 256, 0, stream>>>(
            XCb, Wob + (size_t)L * D_MODEL * D_INNER, H, D_MODEL, D_INNER, nullptr);
    }

    add_ln_kernel<<<NROWS, 256, 0, stream>>>(R, H, normf_w, normf_b, out, nullptr);
}